// Round 1
// baseline (40.855 us; speedup 1.0000x reference)
//
#include <hip/hip_runtime.h>

#define NB 8
#define NS 2048
#define ND 768
#define ND4 192      // ND/4
#define SC 128       // S-chunks for the v column-sum
#define ROWS_PER_CHUNK (NS / SC)  // 16

// ---------------- Kernel A: partial column-sums of v over S ----------------
// grid (SC, NB), block 192. Block (c,b) sums rows [c*16, c*16+16) of v[b].
__global__ __launch_bounds__(192) void vpart_kernel(const float* __restrict__ v,
                                                    float* __restrict__ part) {
    const int c = blockIdx.x;
    const int b = blockIdx.y;
    const int t = threadIdx.x;                 // 0..191  (one float4 column each)
    const float4* v4 = (const float4*)v + ((size_t)b * NS + (size_t)c * ROWS_PER_CHUNK) * ND4 + t;
    float4 acc = make_float4(0.f, 0.f, 0.f, 0.f);
#pragma unroll
    for (int i = 0; i < ROWS_PER_CHUNK; ++i) {
        float4 x = v4[(size_t)i * ND4];
        acc.x += x.x; acc.y += x.y; acc.z += x.z; acc.w += x.w;
    }
    ((float4*)part)[((size_t)c * NB + b) * ND4 + t] = acc;
}

// ---------------- Kernel B: reduce the SC partials -> vsum[NB][ND] ----------------
// grid NB*ND/256, block 256. Deterministic sequential reduce (tiny: 3 MB read).
__global__ __launch_bounds__(256) void vreduce_kernel(const float* __restrict__ part,
                                                      float* __restrict__ vsum) {
    const int i = blockIdx.x * 256 + threadIdx.x;   // 0 .. NB*ND-1
    float acc = 0.f;
#pragma unroll 8
    for (int c = 0; c < SC; ++c) acc += part[(size_t)c * (NB * ND) + i];
    vsum[i] = acc;
}

// ---------------- Kernel C: hvec[b][d] = fc_w[d,:] . vsum[b,:] + fc_b[d] ----------------
// grid ND/4, block 256 (4 waves; wave w owns output row d = blk*4+w).
__global__ __launch_bounds__(256) void matvec_kernel(const float* __restrict__ fcw,
                                                     const float* __restrict__ fcb,
                                                     const float* __restrict__ vsum,
                                                     float* __restrict__ hvec) {
    __shared__ float lds[NB * ND];
    const int t = threadIdx.x;
    for (int i = t; i < NB * ND4; i += 256)
        ((float4*)lds)[i] = ((const float4*)vsum)[i];
    __syncthreads();

    const int w = t >> 6, l = t & 63;
    const int d = blockIdx.x * 4 + w;
    const float4* wrow = (const float4*)(fcw + (size_t)d * ND);
    float acc[NB] = {};
#pragma unroll
    for (int k = 0; k < 3; ++k) {
        const int e4 = l + k * 64;
        const float4 wv = wrow[e4];
#pragma unroll
        for (int b = 0; b < NB; ++b) {
            const float4 vs = ((const float4*)lds)[b * ND4 + e4];
            acc[b] += wv.x * vs.x + wv.y * vs.y + wv.z * vs.z + wv.w * vs.w;
        }
    }
#pragma unroll
    for (int off = 32; off >= 1; off >>= 1)
#pragma unroll
        for (int b = 0; b < NB; ++b)
            acc[b] += __shfl_down(acc[b], off, 64);
    if (l == 0) {
        const float bias = fcb[d];
#pragma unroll
        for (int b = 0; b < NB; ++b) hvec[b * ND + d] = acc[b] + bias;
    }
}

// ---------------- Kernel D: out = LayerNorm(q + hvec[b]) * g + beta ----------------
// grid NB*NS/4, block 256 (4 waves; one wave per output row).
__global__ __launch_bounds__(256) void ln_kernel(const float* __restrict__ q,
                                                 const float* __restrict__ hvec,
                                                 const float* __restrict__ lng,
                                                 const float* __restrict__ lnb,
                                                 float* __restrict__ out) {
    const int w = threadIdx.x >> 6, l = threadIdx.x & 63;
    const int row = blockIdx.x * 4 + w;        // 0 .. NB*NS-1
    const int b = row >> 11;                   // row / NS
    const float4* q4 = (const float4*)q + (size_t)row * ND4;
    const float4* h4 = (const float4*)hvec + (size_t)b * ND4;

    float4 x[3];
    float s = 0.f, sq = 0.f;
#pragma unroll
    for (int k = 0; k < 3; ++k) {
        const int e4 = l + k * 64;
        const float4 qv = q4[e4];
        const float4 hv = h4[e4];
        float4 xv = make_float4(qv.x + hv.x, qv.y + hv.y, qv.z + hv.z, qv.w + hv.w);
        x[k] = xv;
        s  += xv.x + xv.y + xv.z + xv.w;
        sq += xv.x * xv.x + xv.y * xv.y + xv.z * xv.z + xv.w * xv.w;
    }
#pragma unroll
    for (int off = 32; off >= 1; off >>= 1) {
        s  += __shfl_xor(s, off, 64);
        sq += __shfl_xor(sq, off, 64);
    }
    const float inv = 1.0f / (float)ND;
    const float mean = s * inv;
    const float var = sq * inv - mean * mean;
    const float rstd = rsqrtf(var + 1e-5f);

    float4* o4 = (float4*)out + (size_t)row * ND4;
#pragma unroll
    for (int k = 0; k < 3; ++k) {
        const int e4 = l + k * 64;
        const float4 gv = ((const float4*)lng)[e4];
        const float4 bv = ((const float4*)lnb)[e4];
        float4 ov;
        ov.x = (x[k].x - mean) * rstd * gv.x + bv.x;
        ov.y = (x[k].y - mean) * rstd * gv.y + bv.y;
        ov.z = (x[k].z - mean) * rstd * gv.z + bv.z;
        ov.w = (x[k].w - mean) * rstd * gv.w + bv.w;
        o4[e4] = ov;
    }
}

extern "C" void kernel_launch(void* const* d_in, const int* in_sizes, int n_in,
                              void* d_out, int out_size, void* d_ws, size_t ws_size,
                              hipStream_t stream) {
    // setup_inputs order: q, k, v, mask, fc_w, fc_b, ln_g, ln_b, index, typeAdd_Del
    const float* q   = (const float*)d_in[0];
    const float* v   = (const float*)d_in[2];
    const float* fcw = (const float*)d_in[4];
    const float* fcb = (const float*)d_in[5];
    const float* lng = (const float*)d_in[6];
    const float* lnb = (const float*)d_in[7];
    float* out = (float*)d_out;

    // workspace layout (all written before read each call; no cross-call state)
    float* part = (float*)d_ws;                 // SC*NB*ND floats = 3 MB
    float* vsum = part + (size_t)SC * NB * ND;  // NB*ND floats
    float* hvec = vsum + NB * ND;               // NB*ND floats

    vpart_kernel<<<dim3(SC, NB), 192, 0, stream>>>(v, part);
    vreduce_kernel<<<(NB * ND) / 256, 256, 0, stream>>>(part, vsum);
    matvec_kernel<<<ND / 4, 256, 0, stream>>>(fcw, fcb, vsum, hvec);
    ln_kernel<<<(NB * NS) / 4, 256, 0, stream>>>(q, hvec, lng, lnb, out);
}